// Round 7
// baseline (306.472 us; speedup 1.0000x reference)
//
#include <hip/hip_runtime.h>

// ---------------- problem constants (fixed shapes from setup_inputs) --------
constexpr int B_  = 16;
constexpr int L1_ = 65536;
constexpr int L2_ = 131072;
constexpr int S_  = L1_ + L2_;
constexpr int SD_ = 3;
constexpr int KS_ = 8;
constexpr int C_  = 16;
constexpr int E_  = 256;
constexpr int K2_ = L2_ / KS_;   // 16384 y-rows per batch
constexpr int T_  = L1_ / KS_;   // 8192 out-rows per batch
constexpr int NT_ = 32;          // 2048-token tiles per batch

typedef __attribute__((ext_vector_type(8))) short bf16x8;
typedef __attribute__((ext_vector_type(4))) float f32x4;

// ---------------- ws layout (element offsets, 4-byte units) -----------------
// [0, 16384)       : wTb ushort[256][128] bf16 (64 KB)
// [16384, 16896)   : cnt int[512]  (per-(b,tile) mixed counts -> exclusive)
constexpr size_t WT_OFF  = 0;
constexpr size_t CNT_OFF = 16384;

__device__ inline ushort f2bf(float f) {
    uint u = __builtin_bit_cast(uint, f);
    u += 0x7fffu + ((u >> 16) & 1u);       // RNE (inputs finite)
    return (ushort)(u >> 16);
}

// ---------------- prep: w_lat[e][c][s] -> bf16 wTb[e][k], k = s*16+c --------
__global__ void prep_wT(const float* __restrict__ w_lat, ushort* __restrict__ wTb) {
    int e = threadIdx.x;     // 0..255, one block
#pragma unroll 8
    for (int kq = 0; kq < 32; ++kq) {
        ushort u[4];
#pragma unroll
        for (int j = 0; j < 4; ++j) {
            int k = kq * 4 + j;
            int c = k & 15, s = k >> 4;
            u[j] = f2bf(w_lat[e * (C_ * KS_) + c * KS_ + s]);
        }
        uint2 pk;
        pk.x = ((uint)u[1] << 16) | u[0];
        pk.y = ((uint)u[3] << 16) | u[2];
        *(uint2*)(wTb + e * 128 + kq * 4) = pk;
    }
}

// ---------------- pass 1: per-tile mask counts (2048 tokens per tile) -------
__global__ void count_kernel(const int* __restrict__ value, int* __restrict__ cnt) {
    int b = blockIdx.x >> 5, seg = blockIdx.x & 31, tid = threadIdx.x;
    size_t base = (size_t)b * S_ + seg * 2048 + tid * 8;
    const int4 v0 = *(const int4*)(value + base);
    const int4 v1 = *(const int4*)(value + base + 4);
    int c = (v0.x == 2) + (v0.y == 2) + (v0.z == 2) + (v0.w == 2)
          + (v1.x == 2) + (v1.y == 2) + (v1.z == 2) + (v1.w == 2);
    __shared__ int sd[256];
    sd[tid] = c;
    __syncthreads();
    for (int o = 128; o > 0; o >>= 1) {
        if (tid < o) sd[tid] += sd[tid + o];
        __syncthreads();
    }
    if (tid == 0) cnt[blockIdx.x] = sd[0];
}

// ---------------- pass 2: exclusive scan of 32 tile counts per batch --------
__global__ void scan_kernel(int* __restrict__ cnt) {
    int tid = threadIdx.x;                 // 512 threads: b = tid>>5, t = tid&31
    int c = cnt[tid];
    __shared__ int sd[512];
    sd[tid] = c;
    __syncthreads();
    for (int o = 1; o < 32; o <<= 1) {
        int t = ((tid & 31) >= o) ? sd[tid - o] : 0;
        __syncthreads();
        sd[tid] += t;
        __syncthreads();
    }
    cnt[tid] = sd[tid] - c;                // exclusive
}

// ---------------- fused x-build + y-on-demand + latent GEMM (bf16 MFMA) -----
// R2-proven geometry: 512 threads (8 waves), tile = 2048 tokens = 256 out-rows
// x 256 e, W staged in LDS (128 KB total, 1 block/CU). Single delta vs R2:
// y-conv + rank fused into Phase A (smixed compaction, all lanes hot in A2).
// Epilogue uses R6-verified swapped operands: mfma(W,x) -> lane holds 4
// consecutive e -> f32x4 stores.
__global__ __launch_bounds__(512) void out_kernel(
    const int* __restrict__ value, const int* __restrict__ depth,
    const int* __restrict__ pos,
    const float* __restrict__ w_v1, const float* __restrict__ b_v1,
    const float* __restrict__ w_d1, const float* __restrict__ b_d1,
    const float* __restrict__ w_p1, const float* __restrict__ b_p1,
    const float* __restrict__ w_v2, const float* __restrict__ b_v2,
    const float* __restrict__ w_d2, const float* __restrict__ b_d2,
    const float* __restrict__ w_p2, const float* __restrict__ b_p2,
    const float* __restrict__ b_lat,
    const ushort* __restrict__ wTb, const int* __restrict__ cnt,
    float* __restrict__ out) {
    extern __shared__ __align__(16) char smem[];   // 131072 B dynamic
    char* xs  = smem;            // [256 rows][256 B] bf16 swizzled
    char* wsB = smem + 65536;    // [256 e][256 B] bf16 swizzled
    __shared__ float wA[96];     // [0:16) wv1 [16:32) wd1 [32:48) bias1 [48:96) wp1
    __shared__ float w2v[128], w2d[128], w2p[384], w2b[16];
    __shared__ int wtot[8];
    __shared__ ushort smixed[2048];

    const int tid = threadIdx.x;
    const int b = blockIdx.x >> 5, tile = blockIdx.x & 31;
    const int lane = tid & 63, w = tid >> 6;
    const int wm = w >> 1, wn = w & 1;
    const int fr = lane & 15, fk = lane >> 4;

    // -------- stage W into LDS (swizzled): thread covers 128 B of wTb
    {
        const uint4* src = (const uint4*)((const char*)wTb + (size_t)tid * 128);
        uint4 v[8];
#pragma unroll
        for (int q = 0; q < 8; ++q) v[q] = src[q];
        int e = tid >> 1, half = tid & 1, swz = (e & 7) << 4;
#pragma unroll
        for (int q = 0; q < 8; ++q)
            *(uint4*)(wsB + e * 256 + ((half * 128 + q * 16) ^ swz)) = v[q];
    }
    // -------- stage small weights
    if (tid < 16) {
        wA[tid]      = w_v1[tid];
        wA[16 + tid] = w_d1[tid];
        wA[32 + tid] = b_v1[tid] + b_d1[tid] + b_p1[tid] + b_p1[16 + tid] + b_p1[32 + tid];
        w2b[tid]     = b_v2[tid] + b_d2[tid] + b_p2[tid] + b_p2[16 + tid] + b_p2[32 + tid];
    }
    if (tid >= 64 && tid < 112) wA[48 + tid - 64] = w_p1[tid - 64];
    if (tid >= 128 && tid < 256) w2v[tid - 128] = w_v2[tid - 128];
    if (tid >= 256 && tid < 384) w2d[tid - 256] = w_d2[tid - 256];
    if (tid >= 128) { int i = tid - 128; if (i < 384) w2p[i] = w_p2[i]; }

    // -------- token loads (4 contiguous tokens per thread) + mask scan
    size_t gl = (size_t)b * S_ + (size_t)tile * 2048 + tid * 4;
    int4 v4 = *(const int4*)(value + gl);
    int4 d4 = *(const int4*)(depth + gl);
    int4 pA = *(const int4*)(pos + gl * 3);
    int4 pB = *(const int4*)(pos + gl * 3 + 4);
    int4 pC = *(const int4*)(pos + gl * 3 + 8);
    int vls[4] = {v4.x, v4.y, v4.z, v4.w};
    int dls[4] = {d4.x, d4.y, d4.z, d4.w};
    int pp[12] = {pA.x, pA.y, pA.z, pA.w, pB.x, pB.y, pB.z, pB.w, pC.x, pC.y, pC.z, pC.w};
    int mm[4] = {vls[0] == 2, vls[1] == 2, vls[2] == 2, vls[3] == 2};
    int cc = mm[0] + mm[1] + mm[2] + mm[3];
    int incl = cc;
#pragma unroll
    for (int o = 1; o < 64; o <<= 1) {
        int t = __shfl_up(incl, o, 64);
        if (lane >= o) incl += t;
    }
    if (lane == 63) wtot[w] = incl;
    __syncthreads();                                 // B1

    int wexcl = 0, nmixed = 0;
#pragma unroll
    for (int q = 0; q < 8; ++q) {
        nmixed += wtot[q];
        wexcl += (q < w) ? wtot[q] : 0;
    }
    const int cnt_base = cnt[b * NT_ + tile];
    int lrun = wexcl + (incl - cc);                  // local mixed index before token 0

    // -------- A1: non-mixed affine rows into xs; mixed -> smixed
#pragma unroll
    for (int i = 0; i < 4; ++i) {
        int tloc = tid * 4 + i;
        if (mm[i]) {
            smixed[lrun++] = (ushort)tloc;
        } else {
            float fv = (float)vls[i], fd = (float)dls[i];
            float p0 = (float)pp[i * 3], p1 = (float)pp[i * 3 + 1], p2 = (float)pp[i * 3 + 2];
            float xv[16];
#pragma unroll
            for (int c = 0; c < 16; ++c) {
                float acc = wA[32 + c];
                acc = fmaf(fv, wA[c],      acc);
                acc = fmaf(fd, wA[16 + c], acc);
                acc = fmaf(p0, wA[48 + c], acc);
                acc = fmaf(p1, wA[64 + c], acc);
                acc = fmaf(p2, wA[80 + c], acc);
                xv[c] = acc;
            }
            uint pk[8];
#pragma unroll
            for (int q = 0; q < 8; ++q)
                pk[q] = ((uint)f2bf(xv[2 * q + 1]) << 16) | f2bf(xv[2 * q]);
            int row = tloc >> 3, s = tloc & 7, swz = (row & 7) << 4;
            *(uint4*)(xs + row * 256 + ((s * 32)      ^ swz)) = make_uint4(pk[0], pk[1], pk[2], pk[3]);
            *(uint4*)(xs + row * 256 + ((s * 32 + 16) ^ swz)) = make_uint4(pk[4], pk[5], pk[6], pk[7]);
        }
    }
    __syncthreads();                                 // B2

    // -------- A2: compacted y-conv (all lanes active, coalesced gathers)
    for (int j = tid; j < nmixed; j += 512) {
        int tloc = smixed[j];
        size_t g2 = (size_t)b * S_ + L1_ + (size_t)(cnt_base + j) * KS_;
        int4 va = *(const int4*)(value + g2), vb = *(const int4*)(value + g2 + 4);
        int4 da = *(const int4*)(depth + g2), db = *(const int4*)(depth + g2 + 4);
        float vv[8] = {(float)va.x, (float)va.y, (float)va.z, (float)va.w,
                       (float)vb.x, (float)vb.y, (float)vb.z, (float)vb.w};
        float dd[8] = {(float)da.x, (float)da.y, (float)da.z, (float)da.w,
                       (float)db.x, (float)db.y, (float)db.z, (float)db.w};
        float pf[24];
#pragma unroll
        for (int q = 0; q < 6; ++q) {
            int4 t = *(const int4*)(pos + g2 * 3 + q * 4);
            pf[q * 4 + 0] = (float)t.x; pf[q * 4 + 1] = (float)t.y;
            pf[q * 4 + 2] = (float)t.z; pf[q * 4 + 3] = (float)t.w;
        }
        float xv[16];
#pragma unroll
        for (int c = 0; c < 16; ++c) {
            float acc = w2b[c];
#pragma unroll
            for (int s = 0; s < 8; ++s) {
                acc = fmaf(vv[s], w2v[c * 8 + s], acc);
                acc = fmaf(dd[s], w2d[c * 8 + s], acc);
                acc = fmaf(pf[s * 3 + 0], w2p[(0 * 16 + c) * 8 + s], acc);
                acc = fmaf(pf[s * 3 + 1], w2p[(1 * 16 + c) * 8 + s], acc);
                acc = fmaf(pf[s * 3 + 2], w2p[(2 * 16 + c) * 8 + s], acc);
            }
            xv[c] = acc;
        }
        uint pk[8];
#pragma unroll
        for (int q = 0; q < 8; ++q)
            pk[q] = ((uint)f2bf(xv[2 * q + 1]) << 16) | f2bf(xv[2 * q]);
        int row = tloc >> 3, s = tloc & 7, swz = (row & 7) << 4;
        *(uint4*)(xs + row * 256 + ((s * 32)      ^ swz)) = make_uint4(pk[0], pk[1], pk[2], pk[3]);
        *(uint4*)(xs + row * 256 + ((s * 32 + 16) ^ swz)) = make_uint4(pk[4], pk[5], pk[6], pk[7]);
    }
    __syncthreads();                                 // B3

    // -------- MFMA: wave (wm,wn) = rows [wm*64,+64) x e [wn*128,+128)
    // acc[m][n] = sum_kt mfma(W_frag[n], x_frag[m]) -> lane holds 4 consecutive e
    f32x4 acc[4][8];
#pragma unroll
    for (int m = 0; m < 4; ++m)
#pragma unroll
        for (int n = 0; n < 8; ++n)
            acc[m][n] = (f32x4){0.f, 0.f, 0.f, 0.f};

#pragma unroll
    for (int kt = 0; kt < 4; ++kt) {
        bf16x8 wfn[8];
#pragma unroll
        for (int n = 0; n < 8; ++n) {
            int er = wn * 128 + n * 16 + fr;
            wfn[n] = *(const bf16x8*)(wsB + er * 256
                                          + ((kt * 64 + fk * 16) ^ ((er & 7) << 4)));
        }
#pragma unroll
        for (int m = 0; m < 4; ++m) {
            int row = wm * 64 + m * 16 + fr;
            bf16x8 xb = *(const bf16x8*)(xs + row * 256
                                            + ((kt * 64 + fk * 16) ^ ((row & 7) << 4)));
#pragma unroll
            for (int n = 0; n < 8; ++n)
                acc[m][n] = __builtin_amdgcn_mfma_f32_16x16x32_bf16(wfn[n], xb, acc[m][n], 0, 0, 0);
        }
    }

    // -------- epilogue: f32x4 stores (lane = 4 consecutive e)
    size_t rowbase = (size_t)b * T_ + (size_t)tile * 256;
#pragma unroll
    for (int n = 0; n < 8; ++n) {
        int e0 = wn * 128 + n * 16 + fk * 4;
        float4 bl = *(const float4*)(b_lat + e0);
#pragma unroll
        for (int m = 0; m < 4; ++m) {
            int r = wm * 64 + m * 16 + fr;
            f32x4 o4 = {acc[m][n][0] + bl.x, acc[m][n][1] + bl.y,
                        acc[m][n][2] + bl.z, acc[m][n][3] + bl.w};
            *(f32x4*)(out + (rowbase + r) * E_ + e0) = o4;
        }
    }
}

// ---------------- launch ------------------------------------------------------
extern "C" void kernel_launch(void* const* d_in, const int* in_sizes, int n_in,
                              void* d_out, int out_size, void* d_ws, size_t ws_size,
                              hipStream_t stream) {
    const int*   value = (const int*)d_in[0];
    const int*   depth = (const int*)d_in[1];
    const int*   pos   = (const int*)d_in[2];
    // d_in[3] = len1 (static 65536, baked into constants)
    const float* w_v1 = (const float*)d_in[4];
    const float* b_v1 = (const float*)d_in[5];
    const float* w_d1 = (const float*)d_in[6];
    const float* b_d1 = (const float*)d_in[7];
    const float* w_p1 = (const float*)d_in[8];
    const float* b_p1 = (const float*)d_in[9];
    const float* w_v2 = (const float*)d_in[10];
    const float* b_v2 = (const float*)d_in[11];
    const float* w_d2 = (const float*)d_in[12];
    const float* b_d2 = (const float*)d_in[13];
    const float* w_p2 = (const float*)d_in[14];
    const float* b_p2 = (const float*)d_in[15];
    const float* w_lat = (const float*)d_in[16];
    const float* b_lat = (const float*)d_in[17];

    float* outp = (float*)d_out;
    float* wsf  = (float*)d_ws;
    int*   wsi  = (int*)d_ws;

    ushort* wTb = (ushort*)(wsf + WT_OFF);
    int*    cnt = wsi + CNT_OFF;

    prep_wT<<<1, 256, 0, stream>>>(w_lat, wTb);
    count_kernel<<<B_ * NT_, 256, 0, stream>>>(value, cnt);
    scan_kernel<<<1, 512, 0, stream>>>(cnt);
    out_kernel<<<B_ * NT_, 512, 131072, stream>>>(value, depth, pos,
                                                  w_v1, b_v1, w_d1, b_d1, w_p1, b_p1,
                                                  w_v2, b_v2, w_d2, b_d2, w_p2, b_p2,
                                                  b_lat, wTb, cnt, outp);
}

// Round 8
// 305.937 us; speedup vs baseline: 1.0017x; 1.0017x over previous
//
#include <hip/hip_runtime.h>

// ---------------- problem constants (fixed shapes from setup_inputs) --------
constexpr int B_  = 16;
constexpr int L1_ = 65536;
constexpr int L2_ = 131072;
constexpr int S_  = L1_ + L2_;
constexpr int SD_ = 3;
constexpr int KS_ = 8;
constexpr int C_  = 16;
constexpr int E_  = 256;
constexpr int K2_ = L2_ / KS_;   // 16384 y-rows per batch
constexpr int T_  = L1_ / KS_;   // 8192 out-rows per batch
constexpr int NT_ = 32;          // 2048-token tiles per batch

typedef __attribute__((ext_vector_type(8))) short bf16x8;
typedef __attribute__((ext_vector_type(4))) float f32x4;

// ---------------- ws layout (element offsets, 4-byte units) -----------------
// [0, 16384)       : wTb ushort[256][128] bf16 (64 KB)
// [16384, 16896)   : cnt int[512]  (per-(b,tile) mixed counts -> exclusive)
constexpr size_t WT_OFF  = 0;
constexpr size_t CNT_OFF = 16384;

__device__ inline ushort f2bf(float f) {
    uint u = __builtin_bit_cast(uint, f);
    u += 0x7fffu + ((u >> 16) & 1u);       // RNE (inputs finite)
    return (ushort)(u >> 16);
}

// ---------------- prep: w_lat[e][c][s] -> bf16 wTb[e][k], k = s*16+c --------
__global__ void prep_wT(const float* __restrict__ w_lat, ushort* __restrict__ wTb) {
    int e = threadIdx.x;     // 0..255, one block
#pragma unroll 8
    for (int kq = 0; kq < 32; ++kq) {
        ushort u[4];
#pragma unroll
        for (int j = 0; j < 4; ++j) {
            int k = kq * 4 + j;
            int c = k & 15, s = k >> 4;
            u[j] = f2bf(w_lat[e * (C_ * KS_) + c * KS_ + s]);
        }
        uint2 pk;
        pk.x = ((uint)u[1] << 16) | u[0];
        pk.y = ((uint)u[3] << 16) | u[2];
        *(uint2*)(wTb + e * 128 + kq * 4) = pk;
    }
}

// ---------------- pass 1: per-tile mask counts (2048 tokens per tile) -------
__global__ void count_kernel(const int* __restrict__ value, int* __restrict__ cnt) {
    int b = blockIdx.x >> 5, seg = blockIdx.x & 31, tid = threadIdx.x;
    size_t base = (size_t)b * S_ + seg * 2048 + tid * 8;
    const int4 v0 = *(const int4*)(value + base);
    const int4 v1 = *(const int4*)(value + base + 4);
    int c = (v0.x == 2) + (v0.y == 2) + (v0.z == 2) + (v0.w == 2)
          + (v1.x == 2) + (v1.y == 2) + (v1.z == 2) + (v1.w == 2);
    __shared__ int sd[256];
    sd[tid] = c;
    __syncthreads();
    for (int o = 128; o > 0; o >>= 1) {
        if (tid < o) sd[tid] += sd[tid + o];
        __syncthreads();
    }
    if (tid == 0) cnt[blockIdx.x] = sd[0];
}

// ---------------- pass 2: exclusive scan of 32 tile counts per batch --------
__global__ void scan_kernel(int* __restrict__ cnt) {
    int tid = threadIdx.x;                 // 512 threads: b = tid>>5, t = tid&31
    int c = cnt[tid];
    __shared__ int sd[512];
    sd[tid] = c;
    __syncthreads();
    for (int o = 1; o < 32; o <<= 1) {
        int t = ((tid & 31) >= o) ? sd[tid - o] : 0;
        __syncthreads();
        sd[tid] += t;
        __syncthreads();
    }
    cnt[tid] = sd[tid] - c;                // exclusive
}

// ---------------- fused x-build + y-on-demand + latent GEMM (bf16 MFMA) -----
// 512 threads (8 waves), tile = 2048 tokens = 256 out-rows x 256 e, W in LDS.
// REGISTER RULE (R4/R5/R7 post-mortems): 512-thread blocks get a default
// 128-VGPR budget; acc[4][8] (128 VGPR) + operands spilled ~0.6 GB to scratch.
// Fix: MFMA+epilogue split into TWO sequential n-groups (unroll 1), each
// acc[4][4]=64 + wfn[4]=16 + temps ~105 live VGPR < 128 -> no spill possible.
__global__ __launch_bounds__(512) void out_kernel(
    const int* __restrict__ value, const int* __restrict__ depth,
    const int* __restrict__ pos,
    const float* __restrict__ w_v1, const float* __restrict__ b_v1,
    const float* __restrict__ w_d1, const float* __restrict__ b_d1,
    const float* __restrict__ w_p1, const float* __restrict__ b_p1,
    const float* __restrict__ w_v2, const float* __restrict__ b_v2,
    const float* __restrict__ w_d2, const float* __restrict__ b_d2,
    const float* __restrict__ w_p2, const float* __restrict__ b_p2,
    const float* __restrict__ b_lat,
    const ushort* __restrict__ wTb, const int* __restrict__ cnt,
    float* __restrict__ out) {
    extern __shared__ __align__(16) char smem[];   // 131072 B dynamic
    char* xs  = smem;            // [256 rows][256 B] bf16 swizzled
    char* wsB = smem + 65536;    // [256 e][256 B] bf16 swizzled
    __shared__ float wA[96];     // [0:16) wv1 [16:32) wd1 [32:48) bias1 [48:96) wp1
    __shared__ float w2v[128], w2d[128], w2p[384], w2b[16];
    __shared__ int wtot[8];
    __shared__ ushort smixed[2048];

    const int tid = threadIdx.x;
    const int b = blockIdx.x >> 5, tile = blockIdx.x & 31;
    const int lane = tid & 63, w = tid >> 6;
    const int wm = w >> 1, wn = w & 1;
    const int fr = lane & 15, fk = lane >> 4;

    // -------- stage W into LDS (swizzled): thread covers 128 B of wTb
    {
        const uint4* src = (const uint4*)((const char*)wTb + (size_t)tid * 128);
        uint4 v[8];
#pragma unroll
        for (int q = 0; q < 8; ++q) v[q] = src[q];
        int e = tid >> 1, half = tid & 1, swz = (e & 7) << 4;
#pragma unroll
        for (int q = 0; q < 8; ++q)
            *(uint4*)(wsB + e * 256 + ((half * 128 + q * 16) ^ swz)) = v[q];
    }
    // -------- stage small weights
    if (tid < 16) {
        wA[tid]      = w_v1[tid];
        wA[16 + tid] = w_d1[tid];
        wA[32 + tid] = b_v1[tid] + b_d1[tid] + b_p1[tid] + b_p1[16 + tid] + b_p1[32 + tid];
        w2b[tid]     = b_v2[tid] + b_d2[tid] + b_p2[tid] + b_p2[16 + tid] + b_p2[32 + tid];
    }
    if (tid >= 64 && tid < 112) wA[48 + tid - 64] = w_p1[tid - 64];
    if (tid >= 128 && tid < 256) w2v[tid - 128] = w_v2[tid - 128];
    if (tid >= 256 && tid < 384) w2d[tid - 256] = w_d2[tid - 256];
    if (tid >= 128) { int i = tid - 128; if (i < 384) w2p[i] = w_p2[i]; }

    // -------- token loads (4 contiguous tokens per thread) + mask scan
    size_t gl = (size_t)b * S_ + (size_t)tile * 2048 + tid * 4;
    int4 v4 = *(const int4*)(value + gl);
    int4 d4 = *(const int4*)(depth + gl);
    int4 pA = *(const int4*)(pos + gl * 3);
    int4 pB = *(const int4*)(pos + gl * 3 + 4);
    int4 pC = *(const int4*)(pos + gl * 3 + 8);
    int vls[4] = {v4.x, v4.y, v4.z, v4.w};
    int dls[4] = {d4.x, d4.y, d4.z, d4.w};
    int pp[12] = {pA.x, pA.y, pA.z, pA.w, pB.x, pB.y, pB.z, pB.w, pC.x, pC.y, pC.z, pC.w};
    int mm[4] = {vls[0] == 2, vls[1] == 2, vls[2] == 2, vls[3] == 2};
    int cc = mm[0] + mm[1] + mm[2] + mm[3];
    int incl = cc;
#pragma unroll
    for (int o = 1; o < 64; o <<= 1) {
        int t = __shfl_up(incl, o, 64);
        if (lane >= o) incl += t;
    }
    if (lane == 63) wtot[w] = incl;
    __syncthreads();                                 // B1

    int wexcl = 0, nmixed = 0;
#pragma unroll
    for (int q = 0; q < 8; ++q) {
        nmixed += wtot[q];
        wexcl += (q < w) ? wtot[q] : 0;
    }
    const int cnt_base = cnt[b * NT_ + tile];
    int lrun = wexcl + (incl - cc);                  // local mixed index before token 0

    // -------- A1: non-mixed affine rows into xs; mixed -> smixed
#pragma unroll
    for (int i = 0; i < 4; ++i) {
        int tloc = tid * 4 + i;
        if (mm[i]) {
            smixed[lrun++] = (ushort)tloc;
        } else {
            float fv = (float)vls[i], fd = (float)dls[i];
            float p0 = (float)pp[i * 3], p1 = (float)pp[i * 3 + 1], p2 = (float)pp[i * 3 + 2];
            float xv[16];
#pragma unroll
            for (int c = 0; c < 16; ++c) {
                float acc = wA[32 + c];
                acc = fmaf(fv, wA[c],      acc);
                acc = fmaf(fd, wA[16 + c], acc);
                acc = fmaf(p0, wA[48 + c], acc);
                acc = fmaf(p1, wA[64 + c], acc);
                acc = fmaf(p2, wA[80 + c], acc);
                xv[c] = acc;
            }
            uint pk[8];
#pragma unroll
            for (int q = 0; q < 8; ++q)
                pk[q] = ((uint)f2bf(xv[2 * q + 1]) << 16) | f2bf(xv[2 * q]);
            int row = tloc >> 3, s = tloc & 7, swz = (row & 7) << 4;
            *(uint4*)(xs + row * 256 + ((s * 32)      ^ swz)) = make_uint4(pk[0], pk[1], pk[2], pk[3]);
            *(uint4*)(xs + row * 256 + ((s * 32 + 16) ^ swz)) = make_uint4(pk[4], pk[5], pk[6], pk[7]);
        }
    }
    __syncthreads();                                 // B2

    // -------- A2: compacted y-conv (all lanes active, coalesced gathers)
    for (int j = tid; j < nmixed; j += 512) {
        int tloc = smixed[j];
        size_t g2 = (size_t)b * S_ + L1_ + (size_t)(cnt_base + j) * KS_;
        int4 va = *(const int4*)(value + g2), vb = *(const int4*)(value + g2 + 4);
        int4 da = *(const int4*)(depth + g2), db = *(const int4*)(depth + g2 + 4);
        float vv[8] = {(float)va.x, (float)va.y, (float)va.z, (float)va.w,
                       (float)vb.x, (float)vb.y, (float)vb.z, (float)vb.w};
        float dd[8] = {(float)da.x, (float)da.y, (float)da.z, (float)da.w,
                       (float)db.x, (float)db.y, (float)db.z, (float)db.w};
        float pf[24];
#pragma unroll
        for (int q = 0; q < 6; ++q) {
            int4 t = *(const int4*)(pos + g2 * 3 + q * 4);
            pf[q * 4 + 0] = (float)t.x; pf[q * 4 + 1] = (float)t.y;
            pf[q * 4 + 2] = (float)t.z; pf[q * 4 + 3] = (float)t.w;
        }
        float xv[16];
#pragma unroll
        for (int c = 0; c < 16; ++c) {
            float acc = w2b[c];
#pragma unroll
            for (int s = 0; s < 8; ++s) {
                acc = fmaf(vv[s], w2v[c * 8 + s], acc);
                acc = fmaf(dd[s], w2d[c * 8 + s], acc);
                acc = fmaf(pf[s * 3 + 0], w2p[(0 * 16 + c) * 8 + s], acc);
                acc = fmaf(pf[s * 3 + 1], w2p[(1 * 16 + c) * 8 + s], acc);
                acc = fmaf(pf[s * 3 + 2], w2p[(2 * 16 + c) * 8 + s], acc);
            }
            xv[c] = acc;
        }
        uint pk[8];
#pragma unroll
        for (int q = 0; q < 8; ++q)
            pk[q] = ((uint)f2bf(xv[2 * q + 1]) << 16) | f2bf(xv[2 * q]);
        int row = tloc >> 3, s = tloc & 7, swz = (row & 7) << 4;
        *(uint4*)(xs + row * 256 + ((s * 32)      ^ swz)) = make_uint4(pk[0], pk[1], pk[2], pk[3]);
        *(uint4*)(xs + row * 256 + ((s * 32 + 16) ^ swz)) = make_uint4(pk[4], pk[5], pk[6], pk[7]);
    }
    __syncthreads();                                 // B3

    // -------- MFMA + epilogue in TWO n-groups (64 e each) to bound VGPRs.
    // Wave (wm,wn) owns rows [wm*64,+64) x e [wn*128,+128); group g covers
    // e [wn*128+g*64, +64). acc[m][n] = sum_kt mfma(W_frag, x_frag):
    // lane holds 4 consecutive e -> f32x4 stores.
    const size_t rowbase = (size_t)b * T_ + (size_t)tile * 256;
#pragma unroll 1
    for (int g = 0; g < 2; ++g) {
        f32x4 acc[4][4];
#pragma unroll
        for (int m = 0; m < 4; ++m)
#pragma unroll
            for (int n = 0; n < 4; ++n)
                acc[m][n] = (f32x4){0.f, 0.f, 0.f, 0.f};

#pragma unroll
        for (int kt = 0; kt < 4; ++kt) {
            bf16x8 wfn[4];
#pragma unroll
            for (int n = 0; n < 4; ++n) {
                int er = wn * 128 + g * 64 + n * 16 + fr;
                wfn[n] = *(const bf16x8*)(wsB + er * 256
                                              + ((kt * 64 + fk * 16) ^ ((er & 7) << 4)));
            }
#pragma unroll
            for (int m = 0; m < 4; ++m) {
                int row = wm * 64 + m * 16 + fr;
                bf16x8 xb = *(const bf16x8*)(xs + row * 256
                                                + ((kt * 64 + fk * 16) ^ ((row & 7) << 4)));
#pragma unroll
                for (int n = 0; n < 4; ++n)
                    acc[m][n] = __builtin_amdgcn_mfma_f32_16x16x32_bf16(wfn[n], xb, acc[m][n], 0, 0, 0);
            }
        }

        // epilogue for this group: f32x4 stores (lane = 4 consecutive e)
#pragma unroll
        for (int n = 0; n < 4; ++n) {
            int e0 = wn * 128 + g * 64 + n * 16 + fk * 4;
            float4 bl = *(const float4*)(b_lat + e0);
#pragma unroll
            for (int m = 0; m < 4; ++m) {
                int r = wm * 64 + m * 16 + fr;
                f32x4 o4 = {acc[m][n][0] + bl.x, acc[m][n][1] + bl.y,
                            acc[m][n][2] + bl.z, acc[m][n][3] + bl.w};
                *(f32x4*)(out + (rowbase + r) * E_ + e0) = o4;
            }
        }
    }
}

// ---------------- launch ------------------------------------------------------
extern "C" void kernel_launch(void* const* d_in, const int* in_sizes, int n_in,
                              void* d_out, int out_size, void* d_ws, size_t ws_size,
                              hipStream_t stream) {
    const int*   value = (const int*)d_in[0];
    const int*   depth = (const int*)d_in[1];
    const int*   pos   = (const int*)d_in[2];
    // d_in[3] = len1 (static 65536, baked into constants)
    const float* w_v1 = (const float*)d_in[4];
    const float* b_v1 = (const float*)d_in[5];
    const float* w_d1 = (const float*)d_in[6];
    const float* b_d1 = (const float*)d_in[7];
    const float* w_p1 = (const float*)d_in[8];
    const float* b_p1 = (const float*)d_in[9];
    const float* w_v2 = (const float*)d_in[10];
    const float* b_v2 = (const float*)d_in[11];
    const float* w_d2 = (const float*)d_in[12];
    const float* b_d2 = (const float*)d_in[13];
    const float* w_p2 = (const float*)d_in[14];
    const float* b_p2 = (const float*)d_in[15];
    const float* w_lat = (const float*)d_in[16];
    const float* b_lat = (const float*)d_in[17];

    float* outp = (float*)d_out;
    float* wsf  = (float*)d_ws;
    int*   wsi  = (int*)d_ws;

    ushort* wTb = (ushort*)(wsf + WT_OFF);
    int*    cnt = wsi + CNT_OFF;

    prep_wT<<<1, 256, 0, stream>>>(w_lat, wTb);
    count_kernel<<<B_ * NT_, 256, 0, stream>>>(value, cnt);
    scan_kernel<<<1, 512, 0, stream>>>(cnt);
    out_kernel<<<B_ * NT_, 512, 131072, stream>>>(value, depth, pos,
                                                  w_v1, b_v1, w_d1, b_d1, w_p1, b_p1,
                                                  w_v2, b_v2, w_d2, b_d2, w_p2, b_p2,
                                                  b_lat, wTb, cnt, outp);
}

// Round 9
// 135.694 us; speedup vs baseline: 2.2585x; 2.2546x over previous
//
#include <hip/hip_runtime.h>

// ---------------- problem constants (fixed shapes from setup_inputs) --------
constexpr int B_  = 16;
constexpr int L1_ = 65536;
constexpr int L2_ = 131072;
constexpr int S_  = L1_ + L2_;
constexpr int SD_ = 3;
constexpr int KS_ = 8;
constexpr int C_  = 16;
constexpr int E_  = 256;
constexpr int K2_ = L2_ / KS_;   // 16384 y-rows per batch
constexpr int T_  = L1_ / KS_;   // 8192 out-rows per batch
constexpr int NT_ = 64;          // 1024-token tiles per batch

typedef __attribute__((ext_vector_type(8))) short bf16x8;
typedef __attribute__((ext_vector_type(4))) float f32x4;

// ---------------- ws layout (element offsets, 4-byte units) -----------------
// [0, 16384)       : wTb ushort[256][128] bf16 (64 KB)
// [16384, 17408)   : cnt int[1024]  (per-(b,tile) mixed counts -> exclusive)
constexpr size_t WT_OFF  = 0;
constexpr size_t CNT_OFF = 16384;

__device__ inline ushort f2bf(float f) {
    uint u = __builtin_bit_cast(uint, f);
    u += 0x7fffu + ((u >> 16) & 1u);       // RNE (inputs finite)
    return (ushort)(u >> 16);
}

// ---------------- prep: w_lat[e][c][s] -> bf16 wTb[e][k], k = s*16+c --------
__global__ void prep_wT(const float* __restrict__ w_lat, ushort* __restrict__ wTb) {
    int e = threadIdx.x;     // 0..255, one block
#pragma unroll 8
    for (int kq = 0; kq < 32; ++kq) {
        ushort u[4];
#pragma unroll
        for (int j = 0; j < 4; ++j) {
            int k = kq * 4 + j;
            int c = k & 15, s = k >> 4;
            u[j] = f2bf(w_lat[e * (C_ * KS_) + c * KS_ + s]);
        }
        uint2 pk;
        pk.x = ((uint)u[1] << 16) | u[0];
        pk.y = ((uint)u[3] << 16) | u[2];
        *(uint2*)(wTb + e * 128 + kq * 4) = pk;
    }
}

// ---------------- pass 1: per-tile mask counts (1024 tokens per tile) -------
__global__ void count_kernel(const int* __restrict__ value, int* __restrict__ cnt) {
    int b = blockIdx.x >> 6, seg = blockIdx.x & 63, tid = threadIdx.x;
    const int4 v = *(const int4*)(value + (size_t)b * S_ + seg * 1024 + tid * 4);
    int c = (v.x == 2) + (v.y == 2) + (v.z == 2) + (v.w == 2);
    __shared__ int sd[256];
    sd[tid] = c;
    __syncthreads();
    for (int o = 128; o > 0; o >>= 1) {
        if (tid < o) sd[tid] += sd[tid + o];
        __syncthreads();
    }
    if (tid == 0) cnt[blockIdx.x] = sd[0];
}

// ---------------- pass 2: exclusive scan of 64 tile counts per batch --------
__global__ void scan_kernel(int* __restrict__ cnt) {
    int tid = threadIdx.x;                 // 1024 threads: (b = tid>>6, seg = tid&63)
    int c = cnt[tid];
    __shared__ int sd[1024];
    sd[tid] = c;
    __syncthreads();
    for (int o = 1; o < 64; o <<= 1) {
        int t = ((tid & 63) >= o) ? sd[tid - o] : 0;
        __syncthreads();
        sd[tid] += t;
        __syncthreads();
    }
    cnt[tid] = sd[tid] - c;                // exclusive
}

// ---------------- fused x-build + y-on-demand + latent GEMM (bf16 MFMA) -----
// 256 threads (4 waves): R6-proven codegen regime (256-VGPR default budget;
// R7/R8 showed 512-thread blocks cap at 128 VGPR and spill ~400 MB).
// Tile = 1024 tokens = 128 out-rows x 256 e. LDS = xs 32 KB (+~6 KB small)
// -> 3-4 blocks/CU so A/MFMA/store phases of different blocks overlap.
// MFMA runs in TWO e-half phases (acc[4][4] = 64 VGPR each); W fragments
// stream from L2-resident wTb per kt. Epilogue: lane = 4 consecutive e ->
// f32x4 stores (R6/R7/R8-verified mapping).
__global__ __launch_bounds__(256) void out_kernel(
    const int* __restrict__ value, const int* __restrict__ depth,
    const int* __restrict__ pos,
    const float* __restrict__ w_v1, const float* __restrict__ b_v1,
    const float* __restrict__ w_d1, const float* __restrict__ b_d1,
    const float* __restrict__ w_p1, const float* __restrict__ b_p1,
    const float* __restrict__ w_v2, const float* __restrict__ b_v2,
    const float* __restrict__ w_d2, const float* __restrict__ b_d2,
    const float* __restrict__ w_p2, const float* __restrict__ b_p2,
    const float* __restrict__ b_lat,
    const ushort* __restrict__ wTb, const int* __restrict__ cnt,
    float* __restrict__ out) {
    __shared__ __align__(16) char xs[32768];     // [128 rows][256 B] bf16 swizzled
    __shared__ float wA[96];     // [0:16) wv1 [16:32) wd1 [32:48) bias1 [48:96) wp1
    __shared__ float w2v[128], w2d[128], w2p[384], w2b[16];
    __shared__ int wtot[4];
    __shared__ ushort smixed[1024];

    const int tid = threadIdx.x;
    const int b = blockIdx.x >> 6, tile = blockIdx.x & 63;
    const int lane = tid & 63, w = tid >> 6;
    const int wm = w >> 1, wn = w & 1;
    const int fr = lane & 15, fk = lane >> 4;

    // -------- stage small weights
    if (tid < 16) {
        wA[tid]      = w_v1[tid];
        wA[16 + tid] = w_d1[tid];
        wA[32 + tid] = b_v1[tid] + b_d1[tid] + b_p1[tid] + b_p1[16 + tid] + b_p1[32 + tid];
        w2b[tid]     = b_v2[tid] + b_d2[tid] + b_p2[tid] + b_p2[16 + tid] + b_p2[32 + tid];
    }
    if (tid >= 16 && tid < 64)  wA[48 + tid - 16] = w_p1[tid - 16];
    if (tid >= 64 && tid < 192) w2v[tid - 64]     = w_v2[tid - 64];
    if (tid >= 128)             w2d[tid - 128]    = w_d2[tid - 128];
    for (int i = tid; i < 384; i += 256) w2p[i] = w_p2[i];

    // -------- token loads (4 contiguous tokens per thread) + mask scan
    size_t gl = (size_t)b * S_ + (size_t)tile * 1024 + tid * 4;
    int4 v4 = *(const int4*)(value + gl);
    int4 d4 = *(const int4*)(depth + gl);
    int4 pA = *(const int4*)(pos + gl * 3);
    int4 pB = *(const int4*)(pos + gl * 3 + 4);
    int4 pC = *(const int4*)(pos + gl * 3 + 8);
    int vls[4] = {v4.x, v4.y, v4.z, v4.w};
    int dls[4] = {d4.x, d4.y, d4.z, d4.w};
    int pp[12] = {pA.x, pA.y, pA.z, pA.w, pB.x, pB.y, pB.z, pB.w, pC.x, pC.y, pC.z, pC.w};
    int mm[4] = {vls[0] == 2, vls[1] == 2, vls[2] == 2, vls[3] == 2};
    int cc = mm[0] + mm[1] + mm[2] + mm[3];
    int incl = cc;
#pragma unroll
    for (int o = 1; o < 64; o <<= 1) {
        int t = __shfl_up(incl, o, 64);
        if (lane >= o) incl += t;
    }
    if (lane == 63) wtot[w] = incl;
    __syncthreads();                                 // B1

    int wexcl = 0, nmixed = 0;
#pragma unroll
    for (int q = 0; q < 4; ++q) {
        nmixed += wtot[q];
        wexcl += (q < w) ? wtot[q] : 0;
    }
    const int cnt_base = cnt[b * NT_ + tile];
    int lrun = wexcl + (incl - cc);                  // local mixed index before token 0

    // -------- A1: non-mixed affine rows into xs; mixed -> smixed
#pragma unroll
    for (int i = 0; i < 4; ++i) {
        int tloc = tid * 4 + i;
        if (mm[i]) {
            smixed[lrun++] = (ushort)tloc;
        } else {
            float fv = (float)vls[i], fd = (float)dls[i];
            float p0 = (float)pp[i * 3], p1 = (float)pp[i * 3 + 1], p2 = (float)pp[i * 3 + 2];
            float xv[16];
#pragma unroll
            for (int c = 0; c < 16; ++c) {
                float acc = wA[32 + c];
                acc = fmaf(fv, wA[c],      acc);
                acc = fmaf(fd, wA[16 + c], acc);
                acc = fmaf(p0, wA[48 + c], acc);
                acc = fmaf(p1, wA[64 + c], acc);
                acc = fmaf(p2, wA[80 + c], acc);
                xv[c] = acc;
            }
            uint pk[8];
#pragma unroll
            for (int q = 0; q < 8; ++q)
                pk[q] = ((uint)f2bf(xv[2 * q + 1]) << 16) | f2bf(xv[2 * q]);
            int row = tloc >> 3, s = tloc & 7, swz = (row & 7) << 4;
            *(uint4*)(xs + row * 256 + ((s * 32)      ^ swz)) = make_uint4(pk[0], pk[1], pk[2], pk[3]);
            *(uint4*)(xs + row * 256 + ((s * 32 + 16) ^ swz)) = make_uint4(pk[4], pk[5], pk[6], pk[7]);
        }
    }
    __syncthreads();                                 // B2

    // -------- A2: compacted y-conv (all lanes active, coalesced gathers)
    for (int j = tid; j < nmixed; j += 256) {
        int tloc = smixed[j];
        size_t g2 = (size_t)b * S_ + L1_ + (size_t)(cnt_base + j) * KS_;
        int4 va = *(const int4*)(value + g2), vb = *(const int4*)(value + g2 + 4);
        int4 da = *(const int4*)(depth + g2), db = *(const int4*)(depth + g2 + 4);
        float vv[8] = {(float)va.x, (float)va.y, (float)va.z, (float)va.w,
                       (float)vb.x, (float)vb.y, (float)vb.z, (float)vb.w};
        float dd[8] = {(float)da.x, (float)da.y, (float)da.z, (float)da.w,
                       (float)db.x, (float)db.y, (float)db.z, (float)db.w};
        float pf[24];
#pragma unroll
        for (int q = 0; q < 6; ++q) {
            int4 t = *(const int4*)(pos + g2 * 3 + q * 4);
            pf[q * 4 + 0] = (float)t.x; pf[q * 4 + 1] = (float)t.y;
            pf[q * 4 + 2] = (float)t.z; pf[q * 4 + 3] = (float)t.w;
        }
        float xv[16];
#pragma unroll
        for (int c = 0; c < 16; ++c) {
            float acc = w2b[c];
#pragma unroll
            for (int s = 0; s < 8; ++s) {
                acc = fmaf(vv[s], w2v[c * 8 + s], acc);
                acc = fmaf(dd[s], w2d[c * 8 + s], acc);
                acc = fmaf(pf[s * 3 + 0], w2p[(0 * 16 + c) * 8 + s], acc);
                acc = fmaf(pf[s * 3 + 1], w2p[(1 * 16 + c) * 8 + s], acc);
                acc = fmaf(pf[s * 3 + 2], w2p[(2 * 16 + c) * 8 + s], acc);
            }
            xv[c] = acc;
        }
        uint pk[8];
#pragma unroll
        for (int q = 0; q < 8; ++q)
            pk[q] = ((uint)f2bf(xv[2 * q + 1]) << 16) | f2bf(xv[2 * q]);
        int row = tloc >> 3, s = tloc & 7, swz = (row & 7) << 4;
        *(uint4*)(xs + row * 256 + ((s * 32)      ^ swz)) = make_uint4(pk[0], pk[1], pk[2], pk[3]);
        *(uint4*)(xs + row * 256 + ((s * 32 + 16) ^ swz)) = make_uint4(pk[4], pk[5], pk[6], pk[7]);
    }
    __syncthreads();                                 // B3

    // -------- MFMA + epilogue in TWO e-half phases (128 e each).
    // Wave (wm,wn): rows [wm*64,+64) x e [g*128 + wn*64, +64).
    // acc[m][n] = sum_kt mfma(W_frag[n], x_frag[m]); W streamed from L2 wTb.
    const size_t rowbase = (size_t)b * T_ + (size_t)tile * 128;
#pragma unroll 1
    for (int g = 0; g < 2; ++g) {
        f32x4 acc[4][4];
#pragma unroll
        for (int m = 0; m < 4; ++m)
#pragma unroll
            for (int n = 0; n < 4; ++n)
                acc[m][n] = (f32x4){0.f, 0.f, 0.f, 0.f};

#pragma unroll
        for (int kt = 0; kt < 4; ++kt) {
            bf16x8 wfn[4];
#pragma unroll
            for (int n = 0; n < 4; ++n) {
                int er = g * 128 + wn * 64 + n * 16 + fr;
                wfn[n] = *(const bf16x8*)(wTb + (size_t)er * 128 + kt * 32 + fk * 8);
            }
#pragma unroll
            for (int m = 0; m < 4; ++m) {
                int row = wm * 64 + m * 16 + fr;
                bf16x8 xb = *(const bf16x8*)(xs + row * 256
                                                + ((kt * 64 + fk * 16) ^ ((row & 7) << 4)));
#pragma unroll
                for (int n = 0; n < 4; ++n)
                    acc[m][n] = __builtin_amdgcn_mfma_f32_16x16x32_bf16(wfn[n], xb, acc[m][n], 0, 0, 0);
            }
        }

        // epilogue for this half: f32x4 stores (lane = 4 consecutive e)
#pragma unroll
        for (int n = 0; n < 4; ++n) {
            int e0 = g * 128 + wn * 64 + n * 16 + fk * 4;
            float4 bl = *(const float4*)(b_lat + e0);
#pragma unroll
            for (int m = 0; m < 4; ++m) {
                int r = wm * 64 + m * 16 + fr;
                f32x4 o4 = {acc[m][n][0] + bl.x, acc[m][n][1] + bl.y,
                            acc[m][n][2] + bl.z, acc[m][n][3] + bl.w};
                *(f32x4*)(out + (rowbase + r) * E_ + e0) = o4;
            }
        }
    }
}

// ---------------- launch ------------------------------------------------------
extern "C" void kernel_launch(void* const* d_in, const int* in_sizes, int n_in,
                              void* d_out, int out_size, void* d_ws, size_t ws_size,
                              hipStream_t stream) {
    const int*   value = (const int*)d_in[0];
    const int*   depth = (const int*)d_in[1];
    const int*   pos   = (const int*)d_in[2];
    // d_in[3] = len1 (static 65536, baked into constants)
    const float* w_v1 = (const float*)d_in[4];
    const float* b_v1 = (const float*)d_in[5];
    const float* w_d1 = (const float*)d_in[6];
    const float* b_d1 = (const float*)d_in[7];
    const float* w_p1 = (const float*)d_in[8];
    const float* b_p1 = (const float*)d_in[9];
    const float* w_v2 = (const float*)d_in[10];
    const float* b_v2 = (const float*)d_in[11];
    const float* w_d2 = (const float*)d_in[12];
    const float* b_d2 = (const float*)d_in[13];
    const float* w_p2 = (const float*)d_in[14];
    const float* b_p2 = (const float*)d_in[15];
    const float* w_lat = (const float*)d_in[16];
    const float* b_lat = (const float*)d_in[17];

    float* outp = (float*)d_out;
    float* wsf  = (float*)d_ws;
    int*   wsi  = (int*)d_ws;

    ushort* wTb = (ushort*)(wsf + WT_OFF);
    int*    cnt = wsi + CNT_OFF;

    prep_wT<<<1, 256, 0, stream>>>(w_lat, wTb);
    count_kernel<<<B_ * NT_, 256, 0, stream>>>(value, cnt);
    scan_kernel<<<1, 1024, 0, stream>>>(cnt);
    out_kernel<<<B_ * NT_, 256, 0, stream>>>(value, depth, pos,
                                             w_v1, b_v1, w_d1, b_d1, w_p1, b_p1,
                                             w_v2, b_v2, w_d2, b_d2, w_p2, b_p2,
                                             b_lat, wTb, cnt, outp);
}